// Round 4
// baseline (235.113 us; speedup 1.0000x reference)
//
#include <hip/hip_runtime.h>

// hardwiredAttention: out[b,i,h] = sum_j w[b,i,j] * h_t[j,b,h]
//   w = m_i*m_j*relu(domain[cog,r]-d) / max(w)
// R9: contiguous-stream restructure. R3-R8 showed the staging stream pinned
// at 4.7-5.2 B/cyc/CU regardless of path (lds-DMA vs reg) and depth; the
// remaining structural difference vs m13's 10.2 B/cyc copy is access shape:
// column-chunk staging reads 128 B per 2 KB row (DRAM page thrash + latency
// inflation). Fix: producers now read ROWS sequentially (1 KB/wave-instr),
// perform the domain-gather + relu + mask fold themselves, and write the
// full 64x512 w-tile as bf16 into LDS (64 KB, XOR-swizzled rows). Tile-level
// double buffer: each block does TWO (b,i0) tiles; fill(t1) overlaps
// compute(t0). Consumer k-loop is barrier-free: 1 ds_read_b128 A-frag +
// 8 T loads + 8 MFMA per step. Masks fold into w (m binary), so k_scale
// is a pure 1/gmax scale.

#define B_   64
#define N_   512
#define H_   128
#define NCOG 72
#define NRB  72

typedef __bf16 bf16x8 __attribute__((ext_vector_type(8)));
typedef __bf16 bf16x4 __attribute__((ext_vector_type(4)));
typedef float  f32x4  __attribute__((ext_vector_type(4)));
typedef unsigned int u32x4 __attribute__((ext_vector_type(4)));

// ---------- h_t[j][b][h] fp32 -> T[b][h][j] bf16 ----------
__global__ __launch_bounds__(256) void k_transpose(const float* __restrict__ ht,
                                                   __bf16* __restrict__ T) {
    __shared__ __bf16 tile[32][136];
    const int jt = blockIdx.x * 32;
    const int b  = blockIdx.y;
    const int t  = threadIdx.x;
    {
        const int jj = t >> 3;
        const int h0 = (t & 7) << 4;
        const float* src = ht + ((size_t)(jt + jj) * B_ + b) * H_ + h0;
        float4 v0 = *(const float4*)(src + 0);
        float4 v1 = *(const float4*)(src + 4);
        float4 v2 = *(const float4*)(src + 8);
        float4 v3 = *(const float4*)(src + 12);
        __bf16* dst = &tile[jj][h0];
        dst[0]=(__bf16)v0.x; dst[1]=(__bf16)v0.y; dst[2]=(__bf16)v0.z; dst[3]=(__bf16)v0.w;
        dst[4]=(__bf16)v1.x; dst[5]=(__bf16)v1.y; dst[6]=(__bf16)v1.z; dst[7]=(__bf16)v1.w;
        dst[8]=(__bf16)v2.x; dst[9]=(__bf16)v2.y; dst[10]=(__bf16)v2.z; dst[11]=(__bf16)v2.w;
        dst[12]=(__bf16)v3.x; dst[13]=(__bf16)v3.y; dst[14]=(__bf16)v3.z; dst[15]=(__bf16)v3.w;
    }
    __syncthreads();
    {
        const int h  = t >> 1;
        const int j0 = (t & 1) << 4;
        union { bf16x8 v[2]; __bf16 e[16]; } ob;
        #pragma unroll
        for (int q = 0; q < 16; ++q) ob.e[q] = tile[j0 + q][h];
        __bf16* dst = T + ((size_t)b * H_ + h) * N_ + jt + j0;
        *(bf16x8*)(dst + 0) = ob.v[0];
        *(bf16x8*)(dst + 8) = ob.v[1];
    }
}

// ---------- fused kernel: sequential-stream producers + resident w-tile ----------
__global__ __launch_bounds__(512) void k_main(const int* __restrict__ cog,
                                              const int* __restrict__ rmat,
                                              const float* __restrict__ dmat,
                                              const float* __restrict__ mask,
                                              const float* __restrict__ domain,
                                              const __bf16* __restrict__ T,
                                              float* __restrict__ out,
                                              unsigned int* __restrict__ gmax) {
    __shared__ __bf16 wt[2][64][512];       // 131072 B: two full w-tiles (bf16)
    __shared__ float  sdom[NCOG * NRB];     // 20736 B
    __shared__ float  smask[N_];            // 2048 B
    __shared__ float  swmax[8];

    // id bits: [0:2]=xcd, [3:4]=i0-pair, [5:7]=b-high. Same-b blocks share an XCD.
    const int id   = blockIdx.x;            // 0..255
    const int b    = (id & 7) + 8 * (id >> 5);
    const int pair = (id >> 3) & 3;         // tile i0 = pair*128 + tile*64

    const int t    = threadIdx.x;
    const int wave = t >> 6;
    const int lane = t & 63;

    for (int k = t; k < NCOG * NRB; k += 512) sdom[k] = domain[k];
    for (int k = t; k < N_; k += 512) smask[k] = mask[b * N_ + k];

    float wmax = 0.0f;

    // ---- producer: fill wt[tile&1] for tile's 64 rows, sequential reads ----
    const int pw = wave - 4;                               // 0..3 (producers only)
    auto FILL = [&](int tile) {
        const int i0_t = pair * 128 + tile * 64;
        const size_t rowbase0 = ((size_t)b * N_ + i0_t + pw * 16) * N_ + lane * 4;
        // lane's j coordinates: {4*lane..+3, 256+4*lane..+3} (fixed per lane)
        const f32x4 mj0 = *(const f32x4*)&smask[lane * 4];
        const f32x4 mj1 = *(const f32x4*)&smask[256 + lane * 4];

        u32x4 rc[2][2], rr[2][2];
        f32x4 rd[2][2];

        #define PLOAD(u, set)                                                        \
            do {                                                                     \
                const size_t rb_ = rowbase0 + (size_t)(u) * N_;                      \
                rc[set][0] = __builtin_nontemporal_load((const u32x4*)((const unsigned int*)cog + rb_));        \
                rc[set][1] = __builtin_nontemporal_load((const u32x4*)((const unsigned int*)cog + rb_ + 256));  \
                rr[set][0] = __builtin_nontemporal_load((const u32x4*)((const unsigned int*)rmat + rb_));       \
                rr[set][1] = __builtin_nontemporal_load((const u32x4*)((const unsigned int*)rmat + rb_ + 256)); \
                rd[set][0] = __builtin_nontemporal_load((const f32x4*)(dmat + rb_));         \
                rd[set][1] = __builtin_nontemporal_load((const f32x4*)(dmat + rb_ + 256));   \
            } while (0)

        PLOAD(0, 0);
        #pragma unroll
        for (int u = 0; u < 16; ++u) {
            if (u < 15) PLOAD(u + 1, (u + 1) & 1);
            __builtin_amdgcn_sched_barrier(0);   // keep next loads above this gather
            const int set = u & 1;
            const int rl  = pw * 16 + u;                    // local row 0..63
            const float mi = smask[i0_t + rl];              // wave-uniform
            const int swz  = (rl & 7) << 4;
            char* wrow = (char*)&wt[tile & 1][rl][0];
            bf16x4 pa, pb;
            #pragma unroll
            for (int q = 0; q < 4; ++q) {
                float v0 = sdom[rc[set][0][q] * NRB + rr[set][0][q]] - rd[set][0][q];
                v0 = fmaxf(v0, 0.0f) * mj0[q] * mi;
                wmax = fmaxf(wmax, v0);
                pa[q] = (__bf16)v0;
                float v1 = sdom[rc[set][1][q] * NRB + rr[set][1][q]] - rd[set][1][q];
                v1 = fmaxf(v1, 0.0f) * mj1[q] * mi;
                wmax = fmaxf(wmax, v1);
                pb[q] = (__bf16)v1;
            }
            *(bf16x4*)(wrow + ((lane * 8) ^ swz))       = pa;
            *(bf16x4*)(wrow + ((lane * 8 + 512) ^ swz)) = pb;
        }
        #undef PLOAD
    };

    // ---- consumer: barrier-free k-loop over resident w-tile ----
    const int quad = lane >> 4;
    const int lrow = lane & 15;
    const __bf16* Tcol = T + (size_t)b * H_ * N_ + (size_t)lrow * N_ + quad * 8;
    auto COMPUTE = [&](int tile) {
        const int i0_t  = pair * 128 + tile * 64;
        const int row_l = wave * 16 + lrow;
        const char* wrow = (const char*)&wt[tile & 1][row_l][0];
        const int swz = (row_l & 7) << 4;
        f32x4 acc[8];
        #pragma unroll
        for (int i = 0; i < 8; ++i) acc[i] = (f32x4)0.0f;
        #pragma unroll 4
        for (int s = 0; s < 16; ++s) {
            const int kk = s * 32;
            bf16x8 bfb[8];
            #pragma unroll
            for (int nt = 0; nt < 8; ++nt)
                bfb[nt] = *(const bf16x8*)(Tcol + nt * 16 * N_ + kk);
            const bf16x8 af = *(const bf16x8*)(wrow + ((kk * 2 + quad * 16) ^ swz));
            #pragma unroll
            for (int nt = 0; nt < 8; ++nt)
                acc[nt] = __builtin_amdgcn_mfma_f32_16x16x32_bf16(af, bfb[nt], acc[nt], 0, 0, 0);
        }
        const int orow0 = i0_t + wave * 16 + quad * 4;
        #pragma unroll
        for (int nt = 0; nt < 8; ++nt) {
            #pragma unroll
            for (int r = 0; r < 4; ++r)
                out[((size_t)b * N_ + orow0 + r) * H_ + nt * 16 + lrow] = acc[nt][r];
        }
    };

    // ---- schedule: fill0 | barrier | fill1 || compute0 | barrier | compute1 ----
    __syncthreads();                 // sdom/smask ready
    if (wave >= 4) FILL(0);
    __syncthreads();                 // wt[0] ready
    if (wave >= 4) FILL(1); else COMPUTE(0);
    __syncthreads();                 // wt[1] ready
    if (wave < 4) COMPUTE(1);

    // block max -> one atomic (producers carry wmax; consumers contribute 0)
    #pragma unroll
    for (int off = 32; off > 0; off >>= 1)
        wmax = fmaxf(wmax, __shfl_down(wmax, off));
    if (lane == 0) swmax[wave] = wmax;
    __syncthreads();
    if (t == 0) {
        float m = swmax[0];
        #pragma unroll
        for (int w = 1; w < 8; ++w) m = fmaxf(m, swmax[w]);
        atomicMax(gmax, __float_as_uint(m));   // floats >= 0: uint cmp == float cmp
    }
}

// ---------- scale by 1/gmax (masks already folded into w) ----------
__global__ __launch_bounds__(256) void k_scale(float* __restrict__ out,
                                               const unsigned int* __restrict__ gmax) {
    const float inv = 1.0f / __uint_as_float(*gmax);
    const int idx = blockIdx.x * 256 + threadIdx.x;     // 1,048,576 float4s
    float4* p = (float4*)out;
    float4 v = p[idx];
    v.x *= inv; v.y *= inv; v.z *= inv; v.w *= inv;
    p[idx] = v;
}

extern "C" void kernel_launch(void* const* d_in, const int* in_sizes, int n_in,
                              void* d_out, int out_size, void* d_ws, size_t ws_size,
                              hipStream_t stream) {
    const float* ht     = (const float*)d_in[0];   // (N,B,H) f32
    const int*   rmat   = (const int*)  d_in[1];   // (B,N,N) i32
    const float* dmat   = (const float*)d_in[2];   // (B,N,N) f32
    const float* mask   = (const float*)d_in[3];   // (B,N)   f32
    const int*   cog    = (const int*)  d_in[4];   // (B,N,N) i32
    const float* domain = (const float*)d_in[5];   // (72,72) f32
    float* out = (float*)d_out;

    unsigned int* gmax = (unsigned int*)d_ws;
    __bf16* T = (__bf16*)((char*)d_ws + 256);      // 8 MiB bf16 transpose buffer

    hipMemsetAsync(d_ws, 0, 256, stream);          // gmax = 0.0f
    k_transpose<<<dim3(16, 64), 256, 0, stream>>>(ht, T);
    k_main<<<dim3(256), 512, 0, stream>>>(cog, rmat, dmat, mask, domain, T, out, gmax);
    k_scale<<<4096, 256, 0, stream>>>(out, gmax);
}